// Round 9
// baseline (189.544 us; speedup 1.0000x reference)
//
#include <hip/hip_runtime.h>

// Problem constants (from reference)
constexpr int Ni = 4, Ci = 256, Hi = 256, Wi = 256;
constexpr int Bn = 512, PHn = 7, PWn = 7, SRn = 2;
constexpr float SCALEf = 0.25f;

constexpr int NBINS = PHn * PWn;   // 49
constexpr int NSY = PHn * SRn;     // 14
constexpr int NSX = PWn * SRn;     // 14
constexpr int PLANE = Hi * Wi;

// Band decomposition
constexpr int NBANDS   = 8;              // 32-row bands
constexpr int NBUCKETS = Ni * NBANDS;    // 32
constexpr int NPAIRS   = Bn * PHn;       // 3584 (roi, ph) pairs
constexpr int RECW     = 32;             // dwords per pair record (128 B)
constexpr int RSTG     = 37;             // max staged rows (bmax-bmin <= 36, proven)
constexpr int LSTRIDE  = 260;            // floats; mult of 4, not mult of 32
// ws layout (dwords):
//   [0,32) off | [32,64) cnt | [64,96) bmin | [96,128) bmax
//   [128, 128+3584) postab[(roi,ph)] -> pos
//   [4096, 118784) records (3584 * 32)
//   [118784, +6422528) inter[ch][pos*7+pw]  (float)
constexpr int POSTAB_OFF = 128;
constexpr int REC_OFF    = 4096;
constexpr int INTER_OFF  = REC_OFF + NPAIRS * RECW;          // 118784
constexpr size_t WS_DWORDS = (size_t)INTER_OFF + (size_t)Ci * NPAIRS * PWn;  // 6541312
constexpr size_t WS_BYTES  = WS_DWORDS * 4;                  // ~26.2 MB

__device__ __forceinline__ void interp1d(float c, int size,
                                         int& lo, int& hi, float& frac, int& valid)
{
    valid = (c >= -1.0f && c <= (float)size) ? 1 : 0;
    const float cc   = fmaxf(c, 0.0f);
    const float lo_f = floorf(cc);
    lo = min((int)lo_f, size - 1);
    hi = min(lo + 1, size - 1);
    const float c_adj = (lo_f >= (float)(size - 1)) ? (float)(size - 1) : cc;
    frac = c_adj - (float)lo;
}

// ---- Prepass: bucket (roi, ph) pairs by (image, band), precompute records ----
__global__ __launch_bounds__(512) void prepass_kernel(
    const float* __restrict__ rois, unsigned* __restrict__ ws)
{
    __shared__ int s_cnt[NBUCKETS], s_off[NBUCKETS], s_cur[NBUCKETS];
    __shared__ int s_bmin[NBUCKETS], s_bmax[NBUCKETS];
    const int t = threadIdx.x;   // one thread per ROI
    if (t < NBUCKETS) { s_cnt[t] = 0; s_bmin[t] = 255; s_bmax[t] = 0; }
    __syncthreads();

    const int   img = (int)rois[t * 5 + 0];
    const float x1  = rois[t * 5 + 1] * SCALEf - 0.5f;
    const float y1  = rois[t * 5 + 2] * SCALEf - 0.5f;
    const float x2  = rois[t * 5 + 3] * SCALEf - 0.5f;
    const float y2  = rois[t * 5 + 4] * SCALEf - 0.5f;
    const float bw  = (x2 - x1) / (float)PWn;
    const float bh  = (y2 - y1) / (float)PHn;

    unsigned xw[NSX], lxb[NSX];
    for (int s = 0; s < NSX; ++s) {
        const float off = ((float)(s & 1) + 0.5f) * 0.5f;   // 0.25 / 0.75
        const float c = x1 + ((float)(s >> 1) + off) * bw;
        int lo, hi, v; float fr;
        interp1d(c, Wi, lo, hi, fr, v);
        xw[s]  = (unsigned)lo | ((unsigned)hi << 8) | ((unsigned)v << 16);
        lxb[s] = __float_as_uint(fr);
    }

    unsigned rowsw[PHn], lyb0[PHn], lyb1[PHn];
    int vy0a[PHn], vy1a[PHn], bk[PHn];
    for (int ph = 0; ph < PHn; ++ph) {
        int lo0, hi0, v0, lo1, hi1, v1; float f0, f1;
        interp1d(y1 + ((float)ph + 0.25f) * bh, Hi, lo0, hi0, f0, v0);
        interp1d(y1 + ((float)ph + 0.75f) * bh, Hi, lo1, hi1, f1, v1);
        rowsw[ph] = (unsigned)lo0 | ((unsigned)hi0 << 8)
                  | ((unsigned)lo1 << 16) | ((unsigned)hi1 << 24);
        lyb0[ph] = __float_as_uint(f0);
        lyb1[ph] = __float_as_uint(f1);
        vy0a[ph] = v0; vy1a[ph] = v1;
        const int bucket = img * NBANDS + (lo0 >> 5);   // by min sample row
        bk[ph] = bucket;
        atomicAdd(&s_cnt[bucket], 1);
        atomicMin(&s_bmin[bucket], lo0);
        atomicMax(&s_bmax[bucket], max(hi0, hi1));
    }
    __syncthreads();
    if (t == 0) {
        int acc = 0;
        for (int i = 0; i < NBUCKETS; ++i) { s_off[i] = acc; acc += s_cnt[i]; }
    }
    __syncthreads();
    if (t < NBUCKETS) s_cur[t] = s_off[t];
    __syncthreads();

    for (int ph = 0; ph < PHn; ++ph) {
        const int pos = atomicAdd(&s_cur[bk[ph]], 1);
        ws[POSTAB_OFF + t * PHn + ph] = (unsigned)pos;    // inverse map
        unsigned* rec = ws + REC_OFF + (size_t)pos * RECW;
        rec[0] = (unsigned)t | ((unsigned)ph << 12)
               | ((unsigned)vy0a[ph] << 15) | ((unsigned)vy1a[ph] << 16);
        rec[1] = rowsw[ph];
        rec[2] = lyb0[ph];
        rec[3] = lyb1[ph];
        for (int s = 0; s < NSX; ++s) { rec[4 + 2 * s] = xw[s]; rec[5 + 2 * s] = lxb[s]; }
    }
    if (t < NBUCKETS) {
        ws[t]      = (unsigned)s_off[t];
        ws[32 + t] = (unsigned)s_cnt[t];
        ws[64 + t] = (unsigned)s_bmin[t];
        ws[96 + t] = (unsigned)s_bmax[t];
    }
}

// ---- Pass B: per (image, band, channel): dense-stage exact rows, compute
//      pairs, write CONTIGUOUS stream into inter[ch][pos*7+pw] ----
__global__ __launch_bounds__(256) void band_kernel(
    const float* __restrict__ input,
    unsigned* __restrict__ ws)
{
    const int blk  = blockIdx.x;
    const int ch   = blk & 255;
    const int img  = (blk >> 8) & 3;
    const int band = blk >> 10;
    const int bucket = img * NBANDS + band;

    const int cnt = (int)ws[32 + bucket];
    if (cnt == 0) return;
    const int off  = (int)ws[bucket];
    const int bmin = (int)ws[64 + bucket];
    const int bmax = (int)ws[96 + bucket];
    const int R    = bmax - bmin + 1;        // <= 37 (proven)

    __shared__ float s_patch[RSTG * LSTRIDE];   // 38480 B -> 4 blocks/CU
    const int t = threadIdx.x;

    // Exact-range staging, compile-time unrolled (all loads in flight),
    // runtime-predicated to R rows only (keeps FETCH at the R7 level).
    {
        const float4* plane4 = (const float4*)(input + (((size_t)img * Ci + ch) << 16));
        const int n4 = R << 6;                // R * 64 float4s
        float4 v[10];
        #pragma unroll
        for (int u = 0; u < 10; ++u) {
            const int k = t + (u << 8);
            if (k < n4) v[u] = plane4[(bmin << 6) + k];
        }
        #pragma unroll
        for (int u = 0; u < 10; ++u) {
            const int k = t + (u << 8);
            if (k < n4) {
                const int r = k >> 6, c4 = k & 63;
                *(float4*)&s_patch[r * LSTRIDE + (c4 << 2)] = v[u];
            }
        }
    }
    __syncthreads();

    const unsigned* recs = ws + REC_OFF + (size_t)off * RECW;
    float* dst = (float*)(ws + INTER_OFF) + (size_t)ch * (NPAIRS * PWn) + (size_t)off * PWn;
    const int items = cnt * PWn;
    for (int it = t; it < items; it += 256) {
        const int p  = it / 7;
        const int pw = it - p * 7;

        const uint4 ra = *(const uint4*)(recs + (size_t)p * RECW);
        const uint4 rx = *(const uint4*)(recs + (size_t)p * RECW + 4 + (pw << 2));

        const int vy0 = (ra.x >> 15) & 1;
        const int vy1 = (ra.x >> 16) & 1;
        const int a0 = (int)((ra.y      ) & 255u) - bmin;
        const int a1 = (int)((ra.y >>  8) & 255u) - bmin;
        const int a2 = (int)((ra.y >> 16) & 255u) - bmin;
        const int a3 = (int)((ra.y >> 24) & 255u) - bmin;
        const float ly0 = __uint_as_float(ra.z);
        const float ly1 = __uint_as_float(ra.w);

        const int xl0 = rx.x & 255, xh0 = (rx.x >> 8) & 255, vx0 = (rx.x >> 16) & 1;
        const float lx0 = __uint_as_float(rx.y);
        const int xl1 = rx.z & 255, xh1 = (rx.z >> 8) & 255, vx1 = (rx.z >> 16) & 1;
        const float lx1 = __uint_as_float(rx.w);

        const int o0 = a0 * LSTRIDE, o1 = a1 * LSTRIDE,
                  o2 = a2 * LSTRIDE, o3 = a3 * LSTRIDE;
        const float v00 = s_patch[o0 + xl0], v01 = s_patch[o0 + xh0];
        const float v02 = s_patch[o0 + xl1], v03 = s_patch[o0 + xh1];
        const float v10 = s_patch[o1 + xl0], v11 = s_patch[o1 + xh0];
        const float v12 = s_patch[o1 + xl1], v13 = s_patch[o1 + xh1];
        const float v20 = s_patch[o2 + xl0], v21 = s_patch[o2 + xh0];
        const float v22 = s_patch[o2 + xl1], v23 = s_patch[o2 + xh1];
        const float v30 = s_patch[o3 + xl0], v31 = s_patch[o3 + xh0];
        const float v32 = s_patch[o3 + xl1], v33 = s_patch[o3 + xh1];

        const float hy0 = 1.0f - ly0, hy1 = 1.0f - ly1;
        const float hx0 = 1.0f - lx0, hx1 = 1.0f - lx1;
        const float s00 = hy0 * (hx0 * v00 + lx0 * v01) + ly0 * (hx0 * v10 + lx0 * v11);
        const float s01 = hy0 * (hx1 * v02 + lx1 * v03) + ly0 * (hx1 * v12 + lx1 * v13);
        const float s10 = hy1 * (hx0 * v20 + lx0 * v21) + ly1 * (hx0 * v30 + lx0 * v31);
        const float s11 = hy1 * (hx1 * v22 + lx1 * v23) + ly1 * (hx1 * v32 + lx1 * v33);

        const float acc = ((vy0 & vx0) ? s00 : 0.0f) + ((vy0 & vx1) ? s01 : 0.0f)
                        + ((vy1 & vx0) ? s10 : 0.0f) + ((vy1 & vx1) ? s11 : 0.0f);
        dst[it] = acc * 0.25f;   // contiguous full-line stream per block
    }
}

// ---- Pass C: permute inter -> out, coalesced writes ----
__global__ __launch_bounds__(256) void gather_kernel(
    const unsigned* __restrict__ ws,
    float* __restrict__ out)
{
    const int blk = blockIdx.x;      // 2048 = 512 roi x 4 quarters
    const int roi = blk >> 2;
    const int q   = blk & 3;
    const float* inter = (const float*)(ws + INTER_OFF);

    __shared__ int s_pos[PHn];
    const int t = threadIdx.x;
    if (t < PHn) s_pos[t] = (int)ws[POSTAB_OFF + roi * PHn + t];
    __syncthreads();

    const int ebase = q * 3136;      // 3136 = 64 ch * 49
    #pragma unroll
    for (int k = 0; k < 13; ++k) {
        const int el = t + (k << 8);
        if (el < 3136) {
            const int e   = ebase + el;
            const int ch  = e / 49;
            const int bin = e - ch * 49;
            const int ph  = bin / 7;
            const int pw  = bin - ph * 7;
            out[(size_t)roi * (Ci * NBINS) + e] =
                inter[(size_t)ch * (NPAIRS * PWn) + s_pos[ph] * 7 + pw];
        }
    }
}

// ---- Fallback (R4 structure, 98.5 us) if ws too small ----
constexpr int NROWS = 2 * NSY;
constexpr int WSTG = 48;
constexpr int WPAD = 49;
constexpr int CCHUNK = 4;
constexpr int NCHUNKS = Ci / CCHUNK;

__global__ __launch_bounds__(256) void roialign_fallback(
    const float* __restrict__ input,
    const float* __restrict__ rois,
    float* __restrict__ out)
{
    const int blk   = blockIdx.x;
    const int xcd   = blk & 7;
    const int idx   = blk >> 3;
    const int chunk = xcd * 8 + (idx >> 9);
    const int b     = idx & 511;
    const int t = threadIdx.x;

    __shared__ float s_patch[CCHUNK][NROWS][WPAD];
    __shared__ int   s_gy[NROWS];
    __shared__ float s_lyf[NSY];
    __shared__ int   s_yv[NSY];
    __shared__ int   s_xlo[NSX], s_xhi[NSX], s_xv[NSX];
    __shared__ float s_lxf[NSX];
    __shared__ int   s_bidx, s_x0, s_xspan;

    if (t < NSY + NSX) {
        const float r0  = rois[b * 5 + 0];
        const float x1 = rois[b * 5 + 1] * SCALEf - 0.5f;
        const float y1 = rois[b * 5 + 2] * SCALEf - 0.5f;
        const float x2 = rois[b * 5 + 3] * SCALEf - 0.5f;
        const float y2 = rois[b * 5 + 4] * SCALEf - 0.5f;
        const float bin_w = (x2 - x1) / (float)PWn;
        const float bin_h = (y2 - y1) / (float)PHn;
        if (t == 0) s_bidx = (int)r0;
        const bool isY = (t < NSY);
        const int  s   = isY ? t : (t - NSY);
        const float off = ((float)(s & 1) + 0.5f) * 0.5f;
        const float c   = (isY ? y1 : x1) + ((float)(s >> 1) + off) * (isY ? bin_h : bin_w);
        int lo, hi, v; float fr;
        interp1d(c, isY ? Hi : Wi, lo, hi, fr, v);
        if (isY) { s_gy[2*s] = lo; s_gy[2*s+1] = hi; s_lyf[s] = fr; s_yv[s] = v; }
        else     { s_xlo[s] = lo; s_xhi[s] = hi; s_lxf[s] = fr; s_xv[s] = v;
                   if (s == 0) s_x0 = lo; }
    }
    __syncthreads();
    if (t == 0) s_xspan = s_xhi[NSX - 1] - s_x0 + 1;
    __syncthreads();

    const int bidx = s_bidx, x0 = s_x0, xspan = s_xspan;
    {
        const int i  = t % WSTG;
        const int rr = t / WSTG;
        if (t < 240 && i < xspan) {
            const int gxc = min(x0 + i, Wi - 1);
            int gy[6];
            #pragma unroll
            for (int k = 0; k < 6; ++k) { const int r = rr + 5*k; gy[k] = (r < NROWS) ? s_gy[r] : 0; }
            const size_t base_b = (size_t)bidx * Ci * PLANE;
            #pragma unroll
            for (int cl = 0; cl < CCHUNK; ++cl) {
                const float* plane = input + base_b + (size_t)(chunk*CCHUNK + cl) * PLANE;
                #pragma unroll
                for (int k = 0; k < 6; ++k) {
                    const int r = rr + 5*k;
                    if (r < NROWS) s_patch[cl][r][i] = plane[gy[k] * Wi + gxc];
                }
            }
        }
    }
    __syncthreads();
    if (t < CCHUNK * NBINS) {
        const int cl = t / NBINS, bin = t - cl * NBINS;
        const int ph = bin / PWn, pw = bin - ph * PWn;
        float acc = 0.0f;
        #pragma unroll
        for (int iy = 0; iy < SRn; ++iy) {
            const int sy = ph*SRn + iy, rlo = 2*sy;
            const float ly = s_lyf[sy], hy = 1.0f - ly;
            const int vy = s_yv[sy];
            #pragma unroll
            for (int ix = 0; ix < SRn; ++ix) {
                const int sx = pw*SRn + ix;
                const int dxl = s_xlo[sx] - x0, dxh = s_xhi[sx] - x0;
                const float lx = s_lxf[sx], hx = 1.0f - lx;
                const float v = hy*(hx*s_patch[cl][rlo][dxl] + lx*s_patch[cl][rlo][dxh])
                              + ly*(hx*s_patch[cl][rlo+1][dxl] + lx*s_patch[cl][rlo+1][dxh]);
                acc += (vy & s_xv[sx]) ? v : 0.0f;
            }
        }
        out[((size_t)b * Ci + chunk * CCHUNK) * NBINS + t] = acc * 0.25f;
    }
}

extern "C" void kernel_launch(void* const* d_in, const int* in_sizes, int n_in,
                              void* d_out, int out_size, void* d_ws, size_t ws_size,
                              hipStream_t stream) {
    const float* input = (const float*)d_in[0];
    const float* rois  = (const float*)d_in[1];
    float* outp = (float*)d_out;

    if (ws_size >= WS_BYTES) {
        unsigned* ws = (unsigned*)d_ws;
        prepass_kernel<<<1, 512, 0, stream>>>(rois, ws);
        band_kernel<<<Ni * NBANDS * Ci, 256, 0, stream>>>(input, ws);
        gather_kernel<<<Bn * 4, 256, 0, stream>>>(ws, outp);
    } else {
        roialign_fallback<<<Bn * NCHUNKS, 256, 0, stream>>>(input, rois, outp);
    }
}

// Round 10
// 83.615 us; speedup vs baseline: 2.2669x; 2.2669x over previous
//
#include <hip/hip_runtime.h>

// Problem constants (from reference)
constexpr int Ni = 4, Ci = 256, Hi = 256, Wi = 256;
constexpr int Bn = 512, PHn = 7, PWn = 7, SRn = 2;
constexpr float SCALEf = 0.25f;

constexpr int NBINS = PHn * PWn;   // 49
constexpr int NSY = PHn * SRn;     // 14 y samples
constexpr int NSX = PWn * SRn;     // 14 x samples
constexpr int NROWS = 2 * NSY;     // 28 staged rows (ylo/yhi per sample)
constexpr int WSTG = 48;           // max staged row width (6.5*bin_w+2 <= 47)
constexpr int WPAD = 49;           // padded LDS stride (odd -> spreads banks)
constexpr int CCHUNK = 4;          // channels per block (22KB LDS -> 7 blocks/CU)
constexpr int NCHUNKS = Ci / CCHUNK;  // 64
constexpr int PLANE = Hi * Wi;

__global__ __launch_bounds__(256) void roialign_kernel(
    const float* __restrict__ input,
    const float* __restrict__ rois,
    float* __restrict__ out)
{
    // ---- chunk-major + XCD-aware decomposition (R4, proven) ----
    const int blk   = blockIdx.x;
    const int xcd   = blk & 7;
    const int idx   = blk >> 3;              // 0..4095
    const int chunk = xcd * 8 + (idx >> 9);  // 0..63
    const int b     = idx & 511;             // ROI id

    __shared__ float s_patch[CCHUNK][NROWS][WPAD];   // 21952 B
    __shared__ int   s_gyo[NROWS];                   // premultiplied row offsets (gy*Wi)
    __shared__ float s_lyf[NSY];
    __shared__ int   s_yv[NSY];
    __shared__ int   s_xlo[NSX], s_xhi[NSX], s_xv[NSX];
    __shared__ float s_lxf[NSX];
    __shared__ int   s_bidx, s_x0, s_xspan;

    const int t = threadIdx.x;

    // ---- Phase A: per-ROI sample indices/weights (mirrors _interp_1d) ----
    if (t < NSY + NSX) {
        const float r0  = __builtin_nontemporal_load(&rois[b * 5 + 0]);
        const float rx1 = __builtin_nontemporal_load(&rois[b * 5 + 1]);
        const float ry1 = __builtin_nontemporal_load(&rois[b * 5 + 2]);
        const float rx2 = __builtin_nontemporal_load(&rois[b * 5 + 3]);
        const float ry2 = __builtin_nontemporal_load(&rois[b * 5 + 4]);
        const float x1 = rx1 * SCALEf - 0.5f;
        const float y1 = ry1 * SCALEf - 0.5f;
        const float x2 = rx2 * SCALEf - 0.5f;
        const float y2 = ry2 * SCALEf - 0.5f;
        const float bin_w = (x2 - x1) / (float)PWn;
        const float bin_h = (y2 - y1) / (float)PHn;
        if (t == 0) s_bidx = (int)r0;

        const bool isY = (t < NSY);
        const int  s   = isY ? t : (t - NSY);
        const int  p   = s >> 1;            // / SRn
        const int  i   = s & 1;             // % SRn
        const float off   = ((float)i + 0.5f) / (float)SRn;
        const float start = isY ? y1 : x1;
        const float binsz = isY ? bin_h : bin_w;
        const float c     = start + ((float)p + off) * binsz;
        const int   size  = isY ? Hi : Wi;

        const bool  valid = (c >= -1.0f) && (c <= (float)size);
        const float cc    = fmaxf(c, 0.0f);
        const float lo_f  = floorf(cc);
        int lo = min((int)lo_f, size - 1);
        int hi = min(lo + 1, size - 1);
        const float c_adj = (lo_f >= (float)(size - 1)) ? (float)(size - 1) : cc;
        const float frac  = c_adj - (float)lo;

        if (isY) {
            s_gyo[2 * s]     = lo * Wi;
            s_gyo[2 * s + 1] = hi * Wi;
            s_lyf[s] = frac;
            s_yv[s]  = valid ? 1 : 0;
        } else {
            s_xlo[s] = lo; s_xhi[s] = hi; s_lxf[s] = frac; s_xv[s] = valid ? 1 : 0;
            if (s == 0) s_x0 = lo;
            if (s == NSX - 1) {
                // x0 is a pure function of roi values: recompute locally to
                // avoid a second barrier. xs monotone -> x0 = lo of sample 0.
                const float c0  = x1 + 0.25f * bin_w;
                const float cc0 = fmaxf(c0, 0.0f);
                const int   lo0 = min((int)floorf(cc0), Wi - 1);
                s_xspan = hi - lo0 + 1;      // <= 48
            }
        }
    }
    __syncthreads();

    const int bidx  = s_bidx;
    const int x0    = s_x0;
    const int xspan = s_xspan;

    // ---- Phase B: coalesced row staging, exact width, affine indexing ----
    {
        const int i  = t % WSTG;
        const int rr = t / WSTG;
        if (t < 240 && i < xspan) {
            const int gxc = min(x0 + i, Wi - 1);
            int gyo[6];
            #pragma unroll
            for (int k = 0; k < 6; ++k) {
                const int r = rr + 5 * k;
                gyo[k] = (r < NROWS) ? s_gyo[r] : 0;
            }
            const float* base = input + (size_t)bidx * Ci * PLANE
                              + (size_t)(chunk * CCHUNK) * PLANE + gxc;
            #pragma unroll
            for (int cl = 0; cl < CCHUNK; ++cl) {
                const float* plane = base + (size_t)cl * PLANE;
                #pragma unroll
                for (int k = 0; k < 6; ++k) {
                    const int r = rr + 5 * k;
                    if (r < NROWS) {
                        s_patch[cl][r][i] = plane[gyo[k]];
                    }
                }
            }
        }
    }
    __syncthreads();

    // ---- Phase C: compute bins from LDS — single shot (196 <= 256 threads) ----
    if (t < CCHUNK * NBINS) {
        const int cl  = t / NBINS;
        const int bin = t - cl * NBINS;
        const int ph  = bin / PWn;
        const int pw  = bin - ph * PWn;

        float acc = 0.0f;
        #pragma unroll
        for (int iy = 0; iy < SRn; ++iy) {
            const int   sy  = ph * SRn + iy;
            const int   rlo = 2 * sy;
            const float ly  = s_lyf[sy];
            const float hy  = 1.0f - ly;
            const int   vy  = s_yv[sy];
            #pragma unroll
            for (int ix = 0; ix < SRn; ++ix) {
                const int   sx  = pw * SRn + ix;
                const int   dxl = s_xlo[sx] - x0;
                const int   dxh = s_xhi[sx] - x0;
                const float lx  = s_lxf[sx];
                const float hx  = 1.0f - lx;
                const float v11 = s_patch[cl][rlo    ][dxl];
                const float v12 = s_patch[cl][rlo    ][dxh];
                const float v21 = s_patch[cl][rlo + 1][dxl];
                const float v22 = s_patch[cl][rlo + 1][dxh];
                const float v   = hy * (hx * v11 + lx * v12) + ly * (hx * v21 + lx * v22);
                acc += (vy & s_xv[sx]) ? v : 0.0f;
            }
        }
        // Nontemporal: output is write-once, never re-read -> keep L2 for input
        __builtin_nontemporal_store(acc * (1.0f / (SRn * SRn)),
            &out[((size_t)b * Ci + chunk * CCHUNK) * NBINS + t]);
    }
}

extern "C" void kernel_launch(void* const* d_in, const int* in_sizes, int n_in,
                              void* d_out, int out_size, void* d_ws, size_t ws_size,
                              hipStream_t stream) {
    const float* input = (const float*)d_in[0];
    const float* rois  = (const float*)d_in[1];
    float* out = (float*)d_out;

    const int grid = Bn * NCHUNKS;  // 512 * 64 = 32768 blocks
    roialign_kernel<<<grid, 256, 0, stream>>>(input, rois, out);
}